// Round 1
// baseline (1303.299 us; speedup 1.0000x reference)
//
#include <hip/hip_runtime.h>
#include <stdint.h>

typedef unsigned short u16;
typedef unsigned int u32;
typedef __attribute__((ext_vector_type(8))) short bf16x8;
typedef __attribute__((ext_vector_type(4))) float f32x4;

#define T_SEQ 8192
#define DM 1024
#define HD 256

__device__ __forceinline__ u16 f2bf(float f) {
  u32 u = __float_as_uint(f);
  u32 r = (u + 0x7fffu + ((u >> 16) & 1u)) >> 16;
  return (u16)r;
}
__device__ __forceinline__ float bf2f(u16 u) {
  return __uint_as_float(((u32)u) << 16);
}
__device__ __forceinline__ float2 bfp2f(u32 p) {
  float2 r;
  r.x = __uint_as_float(p << 16);
  r.y = __uint_as_float(p & 0xffff0000u);
  return r;
}
__device__ __forceinline__ f32x4 mfma16(bf16x8 a, bf16x8 b, f32x4 c) {
  return __builtin_amdgcn_mfma_f32_16x16x32_bf16(a, b, c, 0, 0, 0);
}

// ---------------- fp32 -> bf16 bulk convert ----------------
__global__ __launch_bounds__(256) void kconv(const float* __restrict__ src, u16* __restrict__ dst, int n4) {
  int i = blockIdx.x * 256 + threadIdx.x;
  if (i < n4) {
    float4 v = reinterpret_cast<const float4*>(src)[i];
    ushort4 s;
    s.x = f2bf(v.x); s.y = f2bf(v.y); s.z = f2bf(v.z); s.w = f2bf(v.w);
    reinterpret_cast<ushort4*>(dst)[i] = s;
  }
}

// ---------------- K1: xb16 + per-head-normalized rk (both (B,T,D) bf16) ----------------
__global__ __launch_bounds__(256) void k_rk(const float* __restrict__ x, u16* __restrict__ xb, u16* __restrict__ rk) {
  const int row = blockIdx.x;
  const int t = threadIdx.x;
  const size_t base = (size_t)row * DM + t * 4;
  float4 v = *reinterpret_cast<const float4*>(&x[base]);
  ushort4 s;
  s.x = f2bf(v.x); s.y = f2bf(v.y); s.z = f2bf(v.z); s.w = f2bf(v.w);
  *reinterpret_cast<ushort4*>(&xb[base]) = s;
  float ss = v.x * v.x + v.y * v.y + v.z * v.z + v.w * v.w;
#pragma unroll
  for (int m = 1; m < 64; m <<= 1) ss += __shfl_xor(ss, m, 64);
  float inv = 1.0f / fmaxf(sqrtf(ss), 1e-12f);
  ushort4 r;
  r.x = f2bf(v.x * inv); r.y = f2bf(v.y * inv); r.z = f2bf(v.z * inv); r.w = f2bf(v.w * inv);
  *reinterpret_cast<ushort4*>(&rk[base]) = r;
}

// ---------------- GEMM: C[M,N] = A[M,K] @ Bt[N,K]^T (bf16 in, fp32 acc) ----------------
// 128x128 tile, BK=64, 256 threads, wave -> 64x64 quadrant, padded LDS (+8 elems/row)
template <bool STORE_BF16>
__global__ __launch_bounds__(256) void gemm_bt(const u16* __restrict__ A, const u16* __restrict__ Bt,
                                               u16* __restrict__ Cb, float* __restrict__ Cf,
                                               const float* __restrict__ addin, int M, int N, int K) {
  __shared__ __align__(16) u16 As[128 * 72];
  __shared__ __align__(16) u16 Bs[128 * 72];
  const int tiles_n = N >> 7;
  const int tm = (blockIdx.x / tiles_n) << 7;
  const int tn = (blockIdx.x % tiles_n) << 7;
  const int t = threadIdx.x;
  const int w = t >> 6, l = t & 63;
  const int lane15 = l & 15, quad = l >> 4;
  const int wm = w & 1, wn = w >> 1;
  const int r0 = t >> 3;          // 0..31
  const int kc = (t & 7) << 3;    // 0..56

  f32x4 acc[4][4];
#pragma unroll
  for (int mi = 0; mi < 4; ++mi)
#pragma unroll
    for (int ni = 0; ni < 4; ++ni) acc[mi][ni] = (f32x4){0.f, 0.f, 0.f, 0.f};

  uint4 pa[4], pb[4];
#pragma unroll
  for (int i = 0; i < 4; ++i) {
    pa[i] = *reinterpret_cast<const uint4*>(&A[(size_t)(tm + r0 + i * 32) * K + kc]);
    pb[i] = *reinterpret_cast<const uint4*>(&Bt[(size_t)(tn + r0 + i * 32) * K + kc]);
  }
  const int NK = K >> 6;
#pragma unroll 1
  for (int kt = 0; kt < NK; ++kt) {
    __syncthreads();
#pragma unroll
    for (int i = 0; i < 4; ++i) {
      *reinterpret_cast<uint4*>(&As[(r0 + i * 32) * 72 + kc]) = pa[i];
      *reinterpret_cast<uint4*>(&Bs[(r0 + i * 32) * 72 + kc]) = pb[i];
    }
    __syncthreads();
    if (kt + 1 < NK) {
      const int k0 = (kt + 1) << 6;
#pragma unroll
      for (int i = 0; i < 4; ++i) {
        pa[i] = *reinterpret_cast<const uint4*>(&A[(size_t)(tm + r0 + i * 32) * K + k0 + kc]);
        pb[i] = *reinterpret_cast<const uint4*>(&Bt[(size_t)(tn + r0 + i * 32) * K + k0 + kc]);
      }
    }
#pragma unroll
    for (int kk = 0; kk < 2; ++kk) {
      bf16x8 af[4], bfr[4];
#pragma unroll
      for (int mi = 0; mi < 4; ++mi)
        af[mi] = *reinterpret_cast<const bf16x8*>(&As[(wm * 64 + mi * 16 + lane15) * 72 + kk * 32 + quad * 8]);
#pragma unroll
      for (int ni = 0; ni < 4; ++ni)
        bfr[ni] = *reinterpret_cast<const bf16x8*>(&Bs[(wn * 64 + ni * 16 + lane15) * 72 + kk * 32 + quad * 8]);
#pragma unroll
      for (int mi = 0; mi < 4; ++mi)
#pragma unroll
        for (int ni = 0; ni < 4; ++ni) acc[mi][ni] = mfma16(af[mi], bfr[ni], acc[mi][ni]);
    }
  }
#pragma unroll
  for (int mi = 0; mi < 4; ++mi)
#pragma unroll
    for (int ni = 0; ni < 4; ++ni)
#pragma unroll
      for (int r = 0; r < 4; ++r) {
        int row = tm + wm * 64 + mi * 16 + quad * 4 + r;
        int col = tn + wn * 64 + ni * 16 + lane15;
        size_t idx = (size_t)row * N + col;
        float vv = acc[mi][ni][r];
        if (STORE_BF16) Cb[idx] = f2bf(vv);
        else Cf[idx] = vv + addin[idx];
      }
}

// ---------------- K2: per-chunk A=inv(I-A0), intra, vA=A@v, wkA=A@wk, wkgT ----------------
__global__ __launch_bounds__(256) void k2(const u16* __restrict__ rk, const u16* __restrict__ v,
                                          u16* __restrict__ vA, u16* __restrict__ wkA,
                                          u16* __restrict__ wkgT, u16* __restrict__ intra,
                                          const float* __restrict__ decay) {
  __shared__ __align__(16) u16 rkext[65][258];
  __shared__ float Am[64][65];
  __shared__ float gp[65];
  const int bx = blockIdx.x;
  const int bh = bx >> 7, n = bx & 127;
  const int b = bh >> 2, h = bh & 3;
  const int t = threadIdx.x;
  if (t <= 64) {
    float gamma = 1.0f / (1.0f + __expf(-decay[h]));
    gp[t] = __powf(gamma, (float)t);
  }
  for (int idx = t; idx < 64 * 65; idx += 256) reinterpret_cast<float*>(Am)[idx] = 0.0f;
  {
    const int tt = t & 127;
    const int rbase = t >> 7;
    for (int rl = rbase; rl < 65; rl += 2) {
      int g = n * 64 - 1 + rl;
      u32 val = 0;
      if (g >= 0) val = *reinterpret_cast<const u32*>(&rk[((size_t)(b * T_SEQ + g)) * DM + h * HD + tt * 2]);
      *reinterpret_cast<u32*>(&rkext[rl][tt * 2]) = val;
    }
  }
  __syncthreads();
  if (t < 64) Am[t][t] = 1.0f;
  // ---- dot phase: M_ww (-> A0 into Am lower) and M_rw (-> intra global) ----
  {
    const int i4 = (t >> 4) << 2;
    const int j4 = (t & 15) << 2;
    float sww[4][4], srw[4][4];
#pragma unroll
    for (int a = 0; a < 4; ++a)
#pragma unroll
      for (int bb = 0; bb < 4; ++bb) { sww[a][bb] = 0.f; srw[a][bb] = 0.f; }
    if (j4 <= i4 + 3) {
      for (int k2x = 0; k2x < 128; ++k2x) {
        float2 wi[5];
        float2 wj[4];
#pragma unroll
        for (int a = 0; a < 5; ++a) wi[a] = bfp2f(*reinterpret_cast<const u32*>(&rkext[i4 + a][k2x * 2]));
#pragma unroll
        for (int bb = 0; bb < 4; ++bb) wj[bb] = bfp2f(*reinterpret_cast<const u32*>(&rkext[j4 + bb][k2x * 2]));
#pragma unroll
        for (int a = 0; a < 4; ++a)
#pragma unroll
          for (int bb = 0; bb < 4; ++bb) {
            sww[a][bb] += wi[a].x * wj[bb].x + wi[a].y * wj[bb].y;
            srw[a][bb] += wi[a + 1].x * wj[bb].x + wi[a + 1].y * wj[bb].y;
          }
      }
    }
    u16* intra_n = intra + (size_t)bx * 4096;
#pragma unroll
    for (int a = 0; a < 4; ++a)
#pragma unroll
      for (int bb = 0; bb < 4; ++bb) {
        int i = i4 + a, j = j4 + bb;
        u16 iv = 0;
        if (j < i) {
          float lfac = gp[i - j];
          Am[i][j] = -sww[a][bb] * lfac;
          iv = f2bf(srw[a][bb] * lfac);
        }
        intra_n[i * 64 + j] = iv;
      }
  }
  __syncthreads();
  // ---- forward substitution: Am := inv(I - A0), unit lower triangular (wave 0) ----
  if (t < 64) {
    const int j = t;
    for (int i = 1; i < 64; ++i) {
      float acc = 0.0f;
      for (int k = 0; k < i; ++k) acc += Am[i][k] * Am[k][j];
      if (j < i) Am[i][j] = acc;
      asm volatile("" ::: "memory");
    }
  }
  __syncthreads();
  // ---- products: thread t owns column i=t of vA/wkA ----
  {
    float accW[64], accV[64];
#pragma unroll
    for (int c = 0; c < 64; ++c) { accW[c] = 0.f; accV[c] = 0.f; }
    const u16* vg = v + ((size_t)(b * T_SEQ + n * 64)) * DM + h * HD + t;
#pragma unroll 1
    for (int k = 0; k < 64; ++k) {
      float wkv = bf2f(rkext[k][t]);
      float vv = bf2f(vg[(size_t)k * DM]);
#pragma unroll
      for (int c = 0; c < 64; ++c) {
        float a = Am[c][k];
        accW[c] += a * wkv;
        accV[c] += a * vv;
      }
    }
    u16* wkA_n = wkA + (size_t)bx * (64 * 256);
    u16* vA_n = vA + (size_t)bx * (64 * 256);
#pragma unroll
    for (int c = 0; c < 64; ++c) {
      wkA_n[c * 256 + t] = f2bf(accW[c]);
      vA_n[c * 256 + t] = f2bf(accV[c]);
    }
  }
  // ---- wkgT[i][c] = wk[c][i] * gamma^(63-c), layout (d, C) ----
  {
    const int c = t & 63;
    const int ig = t >> 6;
    const float scale = gp[63 - c];
    u16* wkg_n = wkgT + (size_t)bx * (256 * 64);
#pragma unroll 4
    for (int m = 0; m < 64; ++m) {
      int i = ig * 64 + m;
      wkg_n[i * 64 + c] = f2bf(bf2f(rkext[c][i]) * scale);
    }
  }
}

// ---------------- K3: sequential scan, state S^T column-block in registers/LDS ----------------
__global__ __launch_bounds__(256) void k3(const u16* __restrict__ rk, const u16* __restrict__ vA,
                                          const u16* __restrict__ wkA, const u16* __restrict__ wkgT,
                                          const u16* __restrict__ intra, const float* __restrict__ decay,
                                          const float* __restrict__ log_alpha, u16* __restrict__ o) {
  __shared__ __align__(16) u16 STb[16][264];   // S^T bf16 copy: [jl][i], padded
  __shared__ __align__(16) u16 vnT[16][72];    // v_new^T [jl][c]
  __shared__ __align__(16) u16 vATl[16][72];   // vA^T staged [jl][c]
  __shared__ __align__(16) u16 oT[16][72];     // o^T [jl][c]
  __shared__ float gp[64];
  const int bh = blockIdx.x >> 4, jb = blockIdx.x & 15;
  const int b = bh >> 2, h = bh & 3;
  const int j0 = jb << 4;
  const int t = threadIdx.x, w = t >> 6, l = t & 63;
  const int lane15 = l & 15, quad = l >> 4;
  const float gamma = 1.0f / (1.0f + __expf(-decay[h]));
  const float alpha = __expf(log_alpha[h]);
  const float gC = __powf(gamma, 64.0f);
  if (t < 64) gp[t] = __powf(gamma, (float)t);
  for (int i = t; i < 2112; i += 256) reinterpret_cast<u32*>(&STb[0][0])[i] = 0u;
  f32x4 Sacc[4];
#pragma unroll
  for (int nt = 0; nt < 4; ++nt) Sacc[nt] = (f32x4){0.f, 0.f, 0.f, 0.f};

  const size_t chb = (size_t)bh * 128;
  const u16* wkA_b = wkA + chb * (64 * 256);
  const u16* vA_b = vA + chb * (64 * 256);
  const u16* wkg_b = wkgT + chb * (256 * 64);
  const u16* intr_b = intra + chb * 4096;
  const int sc = t >> 2;        // 0..63
  const int sj = (t & 3) << 2;  // 0,4,8,12
  __syncthreads();

#pragma unroll 1
  for (int n = 0; n < 128; ++n) {
    __syncthreads();  // (1) STb from prev step stable; LDS buffers reusable
    const u16* wkA_n = wkA_b + (size_t)n * (64 * 256);
    const u16* vA_n = vA_b + (size_t)n * (64 * 256);
    const u16* wkg_n = wkg_b + (size_t)n * (256 * 64);
    const u16* intr_n = intr_b + (size_t)n * 4096;
    const u16* rk_n = rk + ((size_t)(b * T_SEQ + n * 64)) * DM + h * HD;

    // stage vA^T column block
    {
      ushort4 vv = *reinterpret_cast<const ushort4*>(&vA_n[sc * 256 + j0 + sj]);
      vATl[sj + 0][sc] = vv.x;
      vATl[sj + 1][sc] = vv.y;
      vATl[sj + 2][sc] = vv.z;
      vATl[sj + 3][sc] = vv.w;
    }
    // phase A: P^T = S^T @ wkA^T   (wave w handles c-tile w)
    bf16x8 aS[8];
#pragma unroll
    for (int kt = 0; kt < 8; ++kt)
      aS[kt] = *reinterpret_cast<const bf16x8*>(&STb[lane15][kt * 32 + quad * 8]);
    f32x4 accA = (f32x4){0.f, 0.f, 0.f, 0.f};
    {
      const u16* wrow = wkA_n + (w * 16 + lane15) * 256 + quad * 8;
#pragma unroll
      for (int kt = 0; kt < 8; ++kt) {
        bf16x8 bfrag = *reinterpret_cast<const bf16x8*>(&wrow[kt * 32]);
        accA = mfma16(aS[kt], bfrag, accA);
      }
    }
    __syncthreads();  // (2) vATl visible
    // epilogue A: v_new^T = vA^T - P^T
    {
      const int c = w * 16 + lane15;
#pragma unroll
      for (int r = 0; r < 4; ++r) {
        int jl = quad * 4 + r;
        vnT[jl][c] = f2bf(bf2f(vATl[jl][c]) - accA[r]);
      }
    }
    __syncthreads();  // (3) vnT visible
    // phase B: o^T = diag(g^c) * (S^T @ rk^T) + v_new^T @ intra^T, then *alpha
    {
      f32x4 accO = (f32x4){0.f, 0.f, 0.f, 0.f};
      const u16* rrow = rk_n + (size_t)(w * 16 + lane15) * DM + quad * 8;
#pragma unroll
      for (int kt = 0; kt < 8; ++kt) {
        bf16x8 bfrag = *reinterpret_cast<const bf16x8*>(&rrow[kt * 32]);
        accO = mfma16(aS[kt], bfrag, accO);
      }
      const float gc = gp[w * 16 + lane15];
#pragma unroll
      for (int r = 0; r < 4; ++r) accO[r] *= gc;
      const u16* irow = intr_n + (w * 16 + lane15) * 64 + quad * 8;
#pragma unroll
      for (int kt = 0; kt < 2; ++kt) {
        bf16x8 av = *reinterpret_cast<const bf16x8*>(&vnT[lane15][kt * 32 + quad * 8]);
        bf16x8 bfrag = *reinterpret_cast<const bf16x8*>(&irow[kt * 32]);
        accO = mfma16(av, bfrag, accO);
      }
      const int c = w * 16 + lane15;
#pragma unroll
      for (int r = 0; r < 4; ++r) oT[quad * 4 + r][c] = f2bf(accO[r] * alpha);
    }
    __syncthreads();  // (4) oT ready; all STb reads of this step done
    // flush o^T to global (coalesced-ish)
    {
      ushort4 ov;
      ov.x = oT[sj + 0][sc];
      ov.y = oT[sj + 1][sc];
      ov.z = oT[sj + 2][sc];
      ov.w = oT[sj + 3][sc];
      *reinterpret_cast<ushort4*>(&o[((size_t)(b * T_SEQ + n * 64 + sc)) * DM + h * HD + j0 + sj]) = ov;
    }
    // phase C: S^T := gC * S^T + v_new^T @ wkg   (wave w handles i-range [64w, 64w+64))
    {
      bf16x8 aV[2];
#pragma unroll
      for (int kt = 0; kt < 2; ++kt)
        aV[kt] = *reinterpret_cast<const bf16x8*>(&vnT[lane15][kt * 32 + quad * 8]);
#pragma unroll
      for (int nt = 0; nt < 4; ++nt) {
#pragma unroll
        for (int r = 0; r < 4; ++r) Sacc[nt][r] *= gC;
        const u16* grow = wkg_n + (size_t)(w * 64 + nt * 16 + lane15) * 64 + quad * 8;
#pragma unroll
        for (int kt = 0; kt < 2; ++kt) {
          bf16x8 bfrag = *reinterpret_cast<const bf16x8*>(&grow[kt * 32]);
          Sacc[nt] = mfma16(aV[kt], bfrag, Sacc[nt]);
        }
      }
#pragma unroll
      for (int nt = 0; nt < 4; ++nt)
#pragma unroll
        for (int r = 0; r < 4; ++r)
          STb[quad * 4 + r][w * 64 + nt * 16 + lane15] = f2bf(Sacc[nt][r]);
    }
  }
}

extern "C" void kernel_launch(void* const* d_in, const int* in_sizes, int n_in,
                              void* d_out, int out_size, void* d_ws, size_t ws_size,
                              hipStream_t stream) {
  const float* x = (const float*)d_in[0];
  const float* Ww = (const float*)d_in[1];
  const float* Wr = (const float*)d_in[2];
  const float* decay = (const float*)d_in[3];
  const float* lalpha = (const float*)d_in[4];

  char* ws = (char*)d_ws;
  size_t off = 0;
  auto alloc = [&](size_t bytes) {
    char* p = ws + off;
    off += (bytes + 255) & ~(size_t)255;
    return p;
  };
  u16* xb16 = (u16*)alloc(33554432);   // (B,T,D) bf16 x   (later aliased as o)
  u16* rk16 = (u16*)alloc(33554432);   // (B,T,D) bf16 rk
  u16* v16  = (u16*)alloc(33554432);   // (B,T,D) bf16 v
  u16* vAb  = (u16*)alloc(33554432);   // (BH,N,C,d)
  u16* wkAb = (u16*)alloc(33554432);   // (BH,N,C,d)
  u16* wkgb = (u16*)alloc(33554432);   // (BH,N,d,C)
  u16* intrb = (u16*)alloc(8388608);   // (BH,N,C,C)
  u16* Ww16 = (u16*)alloc(2097152);
  u16* Wr16 = (u16*)alloc(2097152);
  u16* o16 = xb16;  // alias: xb16 dead after GEMM1

  kconv<<<1024, 256, 0, stream>>>(Ww, Ww16, 262144);
  kconv<<<1024, 256, 0, stream>>>(Wr, Wr16, 262144);
  k_rk<<<16384, 256, 0, stream>>>(x, xb16, rk16);
  gemm_bt<true><<<1024, 256, 0, stream>>>(xb16, Ww16, v16, nullptr, nullptr, 16384, 1024, 1024);
  k2<<<1024, 256, 0, stream>>>(rk16, v16, vAb, wkAb, wkgb, intrb, decay);
  k3<<<128, 256, 0, stream>>>(rk16, vAb, wkAb, wkgb, intrb, decay, lalpha, o16);
  gemm_bt<false><<<1024, 256, 0, stream>>>(o16, Wr16, nullptr, (float*)d_out, x, 16384, 1024, 1024);
}

// Round 2
// 1042.846 us; speedup vs baseline: 1.2498x; 1.2498x over previous
//
#include <hip/hip_runtime.h>
#include <stdint.h>

typedef unsigned short u16;
typedef unsigned int u32;
typedef __attribute__((ext_vector_type(8))) short bf16x8;
typedef __attribute__((ext_vector_type(4))) float f32x4;

#define T_SEQ 8192
#define DM 1024
#define HD 256

__device__ __forceinline__ u16 f2bf(float f) {
  u32 u = __float_as_uint(f);
  u32 r = (u + 0x7fffu + ((u >> 16) & 1u)) >> 16;
  return (u16)r;
}
__device__ __forceinline__ float bf2f(u16 u) {
  return __uint_as_float(((u32)u) << 16);
}
__device__ __forceinline__ float2 bfp2f(u32 p) {
  float2 r;
  r.x = __uint_as_float(p << 16);
  r.y = __uint_as_float(p & 0xffff0000u);
  return r;
}
__device__ __forceinline__ f32x4 mfma16(bf16x8 a, bf16x8 b, f32x4 c) {
  return __builtin_amdgcn_mfma_f32_16x16x32_bf16(a, b, c, 0, 0, 0);
}
// async global->LDS, 16B per lane. LDS dest must be wave-uniform base + lane*16.
__device__ __forceinline__ void gl2lds16(const u16* g, u16* l) {
  __builtin_amdgcn_global_load_lds(
      (const __attribute__((address_space(1))) u32*)(uintptr_t)g,
      (__attribute__((address_space(3))) u32*)(u32)(uintptr_t)l, 16, 0, 0);
}

// ---------------- fp32 -> bf16 bulk convert ----------------
__global__ __launch_bounds__(256) void kconv(const float* __restrict__ src, u16* __restrict__ dst, int n4) {
  int i = blockIdx.x * 256 + threadIdx.x;
  if (i < n4) {
    float4 v = reinterpret_cast<const float4*>(src)[i];
    ushort4 s;
    s.x = f2bf(v.x); s.y = f2bf(v.y); s.z = f2bf(v.z); s.w = f2bf(v.w);
    reinterpret_cast<ushort4*>(dst)[i] = s;
  }
}

// ---------------- K1: xb16 + per-head-normalized rk (both (B,T,D) bf16) ----------------
__global__ __launch_bounds__(256) void k_rk(const float* __restrict__ x, u16* __restrict__ xb, u16* __restrict__ rk) {
  const int row = blockIdx.x;
  const int t = threadIdx.x;
  const size_t base = (size_t)row * DM + t * 4;
  float4 v = *reinterpret_cast<const float4*>(&x[base]);
  ushort4 s;
  s.x = f2bf(v.x); s.y = f2bf(v.y); s.z = f2bf(v.z); s.w = f2bf(v.w);
  *reinterpret_cast<ushort4*>(&xb[base]) = s;
  float ss = v.x * v.x + v.y * v.y + v.z * v.z + v.w * v.w;
#pragma unroll
  for (int m = 1; m < 64; m <<= 1) ss += __shfl_xor(ss, m, 64);
  float inv = 1.0f / fmaxf(sqrtf(ss), 1e-12f);
  ushort4 r;
  r.x = f2bf(v.x * inv); r.y = f2bf(v.y * inv); r.z = f2bf(v.z * inv); r.w = f2bf(v.w * inv);
  *reinterpret_cast<ushort4*>(&rk[base]) = r;
}

// ---------------- GEMM: C[M,N] = A[M,K] @ Bt[N,K]^T (bf16 in, fp32 acc) ----------------
// 128x128 tile, BK=64, 256 threads, m97 structure: global_load_lds width-16 staging.
template <bool STORE_BF16>
__global__ __launch_bounds__(256) void gemm_bt(const u16* __restrict__ A, const u16* __restrict__ Bt,
                                               u16* __restrict__ Cb, float* __restrict__ Cf,
                                               const float* __restrict__ addin, int M, int N, int K) {
  __shared__ __align__(16) u16 As[128 * 64];
  __shared__ __align__(16) u16 Bs[128 * 64];
  const int tiles_n = N >> 7;
  const int tm = (blockIdx.x / tiles_n) << 7;
  const int tn = (blockIdx.x % tiles_n) << 7;
  const int t = threadIdx.x;
  const int w = t >> 6, l = t & 63;
  const int lane15 = l & 15, quad = l >> 4;
  const int wm = w & 1, wn = w >> 1;
  const int r0 = t >> 3;          // 0..31
  const int kc = (t & 7) << 3;    // 0..56 (u16 units, 16B chunks)

  f32x4 acc[4][4];
#pragma unroll
  for (int mi = 0; mi < 4; ++mi)
#pragma unroll
    for (int ni = 0; ni < 4; ++ni) acc[mi][ni] = (f32x4){0.f, 0.f, 0.f, 0.f};

  const int NK = K >> 6;
#pragma unroll 1
  for (int kt = 0; kt < NK; ++kt) {
    __syncthreads();  // prior tile's LDS reads complete
    const int k0 = kt << 6;
#pragma unroll
    for (int j = 0; j < 4; ++j) {
      gl2lds16(&A[(size_t)(tm + r0 + j * 32) * K + k0 + kc], &As[(r0 + j * 32) * 64 + kc]);
      gl2lds16(&Bt[(size_t)(tn + r0 + j * 32) * K + k0 + kc], &Bs[(r0 + j * 32) * 64 + kc]);
    }
    __syncthreads();  // drains vmcnt -> staged data visible
#pragma unroll
    for (int kk = 0; kk < 2; ++kk) {
      bf16x8 af[4], bfr[4];
#pragma unroll
      for (int mi = 0; mi < 4; ++mi)
        af[mi] = *reinterpret_cast<const bf16x8*>(&As[(wm * 64 + mi * 16 + lane15) * 64 + kk * 32 + quad * 8]);
#pragma unroll
      for (int ni = 0; ni < 4; ++ni)
        bfr[ni] = *reinterpret_cast<const bf16x8*>(&Bs[(wn * 64 + ni * 16 + lane15) * 64 + kk * 32 + quad * 8]);
#pragma unroll
      for (int mi = 0; mi < 4; ++mi)
#pragma unroll
        for (int ni = 0; ni < 4; ++ni) acc[mi][ni] = mfma16(af[mi], bfr[ni], acc[mi][ni]);
    }
  }
#pragma unroll
  for (int mi = 0; mi < 4; ++mi)
#pragma unroll
    for (int ni = 0; ni < 4; ++ni)
#pragma unroll
      for (int r = 0; r < 4; ++r) {
        int row = tm + wm * 64 + mi * 16 + quad * 4 + r;
        int col = tn + wn * 64 + ni * 16 + lane15;
        size_t idx = (size_t)row * N + col;
        float vv = acc[mi][ni][r];
        if (STORE_BF16) Cb[idx] = f2bf(vv);
        else Cf[idx] = vv + addin[idx];
      }
}

// ---------------- K2: per-chunk A=inv(I-A0), intra, vA=A@v, wkA=A@wk, wkgT ----------------
__global__ __launch_bounds__(256) void k2(const u16* __restrict__ rk, const u16* __restrict__ v,
                                          u16* __restrict__ vA, u16* __restrict__ wkA,
                                          u16* __restrict__ wkgT, u16* __restrict__ intra,
                                          const float* __restrict__ decay) {
  __shared__ __align__(16) u16 rkext[65][258];
  __shared__ float Am[64][65];
  __shared__ float gp[65];
  const int bx = blockIdx.x;
  const int bh = bx >> 7, n = bx & 127;
  const int b = bh >> 2, h = bh & 3;
  const int t = threadIdx.x;
  if (t <= 64) {
    float gamma = 1.0f / (1.0f + __expf(-decay[h]));
    gp[t] = __powf(gamma, (float)t);
  }
  for (int idx = t; idx < 64 * 65; idx += 256) reinterpret_cast<float*>(Am)[idx] = 0.0f;
  {
    const int tt = t & 127;
    const int rbase = t >> 7;
    for (int rl = rbase; rl < 65; rl += 2) {
      int g = n * 64 - 1 + rl;
      u32 val = 0;
      if (g >= 0) val = *reinterpret_cast<const u32*>(&rk[((size_t)(b * T_SEQ + g)) * DM + h * HD + tt * 2]);
      *reinterpret_cast<u32*>(&rkext[rl][tt * 2]) = val;
    }
  }
  __syncthreads();
  if (t < 64) Am[t][t] = 1.0f;
  // ---- dot phase: M_ww (-> A0 into Am lower) and M_rw (-> intra global) ----
  {
    const int i4 = (t >> 4) << 2;
    const int j4 = (t & 15) << 2;
    float sww[4][4], srw[4][4];
#pragma unroll
    for (int a = 0; a < 4; ++a)
#pragma unroll
      for (int bb = 0; bb < 4; ++bb) { sww[a][bb] = 0.f; srw[a][bb] = 0.f; }
    if (j4 <= i4 + 3) {
      for (int k2x = 0; k2x < 128; ++k2x) {
        float2 wi[5];
        float2 wj[4];
#pragma unroll
        for (int a = 0; a < 5; ++a) wi[a] = bfp2f(*reinterpret_cast<const u32*>(&rkext[i4 + a][k2x * 2]));
#pragma unroll
        for (int bb = 0; bb < 4; ++bb) wj[bb] = bfp2f(*reinterpret_cast<const u32*>(&rkext[j4 + bb][k2x * 2]));
#pragma unroll
        for (int a = 0; a < 4; ++a)
#pragma unroll
          for (int bb = 0; bb < 4; ++bb) {
            sww[a][bb] += wi[a].x * wj[bb].x + wi[a].y * wj[bb].y;
            srw[a][bb] += wi[a + 1].x * wj[bb].x + wi[a + 1].y * wj[bb].y;
          }
      }
    }
    u16* intra_n = intra + (size_t)bx * 4096;
#pragma unroll
    for (int a = 0; a < 4; ++a)
#pragma unroll
      for (int bb = 0; bb < 4; ++bb) {
        int i = i4 + a, j = j4 + bb;
        u16 iv = 0;
        if (j < i) {
          float lfac = gp[i - j];
          Am[i][j] = -sww[a][bb] * lfac;
          iv = f2bf(srw[a][bb] * lfac);
        }
        intra_n[i * 64 + j] = iv;
      }
  }
  __syncthreads();
  // ---- forward substitution: Am := inv(I - A0), unit lower triangular (wave 0) ----
  if (t < 64) {
    const int j = t;
    for (int i = 1; i < 64; ++i) {
      float acc = 0.0f;
      for (int k = 0; k < i; ++k) acc += Am[i][k] * Am[k][j];
      if (j < i) Am[i][j] = acc;
      asm volatile("" ::: "memory");
    }
  }
  __syncthreads();
  // ---- products: thread t owns column i=t of vA/wkA ----
  {
    float accW[64], accV[64];
#pragma unroll
    for (int c = 0; c < 64; ++c) { accW[c] = 0.f; accV[c] = 0.f; }
    const u16* vg = v + ((size_t)(b * T_SEQ + n * 64)) * DM + h * HD + t;
#pragma unroll 1
    for (int k = 0; k < 64; ++k) {
      float wkv = bf2f(rkext[k][t]);
      float vv = bf2f(vg[(size_t)k * DM]);
#pragma unroll
      for (int c = 0; c < 64; ++c) {
        float a = Am[c][k];
        accW[c] += a * wkv;
        accV[c] += a * vv;
      }
    }
    u16* wkA_n = wkA + (size_t)bx * (64 * 256);
    u16* vA_n = vA + (size_t)bx * (64 * 256);
#pragma unroll
    for (int c = 0; c < 64; ++c) {
      wkA_n[c * 256 + t] = f2bf(accW[c]);
      vA_n[c * 256 + t] = f2bf(accV[c]);
    }
  }
  // ---- wkgT[i][c] = wk[c][i] * gamma^(63-c), layout (d, C) ----
  {
    const int c = t & 63;
    const int ig = t >> 6;
    const float scale = gp[63 - c];
    u16* wkg_n = wkgT + (size_t)bx * (256 * 64);
#pragma unroll 4
    for (int m = 0; m < 64; ++m) {
      int i = ig * 64 + m;
      wkg_n[i * 64 + c] = f2bf(bf2f(rkext[c][i]) * scale);
    }
  }
}

// ---------------- K3: sequential scan, S^T column-block, register-prefetch pipeline ----------------
__global__ __launch_bounds__(256, 1) void k3(const u16* __restrict__ rk, const u16* __restrict__ vA,
                                             const u16* __restrict__ wkA, const u16* __restrict__ wkgT,
                                             const u16* __restrict__ intra, const float* __restrict__ decay,
                                             const float* __restrict__ log_alpha, u16* __restrict__ o) {
  __shared__ __align__(16) u16 STb[16][264];   // S^T bf16 copy: [jl][i], padded
  __shared__ __align__(16) u16 vnT[16][72];    // v_new^T [jl][c]
  const int bh = blockIdx.x >> 4, jb = blockIdx.x & 15;
  const int b = bh >> 2, h = bh & 3;
  const int j0 = jb << 4;
  const int t = threadIdx.x, w = t >> 6, l = t & 63;
  const int lane15 = l & 15, quad = l >> 4;
  const float gamma = 1.0f / (1.0f + __expf(-decay[h]));
  const float alpha = __expf(log_alpha[h]);
  const float gC = __powf(gamma, 64.0f);
  const int c = w * 16 + lane15;               // chunk-row this lane owns in phases A/B
  const float gc = __powf(gamma, (float)c);
  for (int i = t; i < 2112; i += 256) reinterpret_cast<u32*>(&STb[0][0])[i] = 0u;
  f32x4 Sacc[4];
#pragma unroll
  for (int nt = 0; nt < 4; ++nt) Sacc[nt] = (f32x4){0.f, 0.f, 0.f, 0.f};

  const size_t chb = (size_t)bh * 128;
  const u16* wkA_b = wkA + chb * (64 * 256);
  const u16* vA_b = vA + chb * (64 * 256);
  const u16* wkg_b = wkgT + chb * (256 * 64);
  const u16* intr_b = intra + chb * 4096;
  const u16* rk_b = rk + ((size_t)(b * T_SEQ)) * DM + h * HD;

  // ---- register prefetch buffers (next chunk) ----
  bf16x8 p_wkA[8], p_rk[8], p_wkg[8], p_in[2];
  ushort4 p_vA;
  auto prefetch = [&](int n) {
    const u16* wkA_n = wkA_b + (size_t)n * (64 * 256);
    const u16* vA_n = vA_b + (size_t)n * (64 * 256);
    const u16* wkg_n = wkg_b + (size_t)n * (256 * 64);
    const u16* intr_n = intr_b + (size_t)n * 4096;
    const u16* rk_n = rk_b + (size_t)n * 64 * DM;
    const u16* wrow = wkA_n + c * 256 + quad * 8;
    const u16* rrow = rk_n + (size_t)c * DM + quad * 8;
#pragma unroll
    for (int kt = 0; kt < 8; ++kt) {
      p_wkA[kt] = *reinterpret_cast<const bf16x8*>(&wrow[kt * 32]);
      p_rk[kt] = *reinterpret_cast<const bf16x8*>(&rrow[kt * 32]);
    }
    const u16* irow = intr_n + c * 64 + quad * 8;
#pragma unroll
    for (int kt = 0; kt < 2; ++kt) p_in[kt] = *reinterpret_cast<const bf16x8*>(&irow[kt * 32]);
#pragma unroll
    for (int nt = 0; nt < 4; ++nt)
#pragma unroll
      for (int kt = 0; kt < 2; ++kt)
        p_wkg[nt * 2 + kt] =
            *reinterpret_cast<const bf16x8*>(&wkg_n[(size_t)(w * 64 + nt * 16 + lane15) * 64 + kt * 32 + quad * 8]);
    p_vA = *reinterpret_cast<const ushort4*>(&vA_n[c * 256 + j0 + quad * 4]);
  };
  prefetch(0);

#pragma unroll 1
  for (int n = 0; n < 128; ++n) {
    // consume prefetched, issue next
    bf16x8 c_wkA[8], c_rk[8], c_wkg[8], c_in[2];
    ushort4 c_vA = p_vA;
#pragma unroll
    for (int kt = 0; kt < 8; ++kt) { c_wkA[kt] = p_wkA[kt]; c_rk[kt] = p_rk[kt]; c_wkg[kt] = p_wkg[kt]; }
#pragma unroll
    for (int kt = 0; kt < 2; ++kt) c_in[kt] = p_in[kt];
    if (n < 127) prefetch(n + 1);

    __syncthreads();  // (1) STb from prev step's phase C stable
    bf16x8 aS[8];
#pragma unroll
    for (int kt = 0; kt < 8; ++kt)
      aS[kt] = *reinterpret_cast<const bf16x8*>(&STb[lane15][kt * 32 + quad * 8]);
    // phase A: P^T = S^T @ wkA^T; v_new^T = vA^T - P^T
    f32x4 accA = (f32x4){0.f, 0.f, 0.f, 0.f};
#pragma unroll
    for (int kt = 0; kt < 8; ++kt) accA = mfma16(aS[kt], c_wkA[kt], accA);
    vnT[quad * 4 + 0][c] = f2bf(bf2f(c_vA.x) - accA[0]);
    vnT[quad * 4 + 1][c] = f2bf(bf2f(c_vA.y) - accA[1]);
    vnT[quad * 4 + 2][c] = f2bf(bf2f(c_vA.z) - accA[2]);
    vnT[quad * 4 + 3][c] = f2bf(bf2f(c_vA.w) - accA[3]);
    __syncthreads();  // (2) vnT visible
    bf16x8 aV[2];
#pragma unroll
    for (int kt = 0; kt < 2; ++kt)
      aV[kt] = *reinterpret_cast<const bf16x8*>(&vnT[lane15][kt * 32 + quad * 8]);
    // phase B: o^T = diag(g^c)*(S^T @ rk^T) + v_new^T @ intra^T, *alpha, direct store
    {
      f32x4 accO = (f32x4){0.f, 0.f, 0.f, 0.f};
#pragma unroll
      for (int kt = 0; kt < 8; ++kt) accO = mfma16(aS[kt], c_rk[kt], accO);
#pragma unroll
      for (int r = 0; r < 4; ++r) accO[r] *= gc;
#pragma unroll
      for (int kt = 0; kt < 2; ++kt) accO = mfma16(aV[kt], c_in[kt], accO);
      ushort4 ov;
      ov.x = f2bf(accO[0] * alpha);
      ov.y = f2bf(accO[1] * alpha);
      ov.z = f2bf(accO[2] * alpha);
      ov.w = f2bf(accO[3] * alpha);
      *reinterpret_cast<ushort4*>(&o[((size_t)(b * T_SEQ + n * 64 + c)) * DM + h * HD + j0 + quad * 4]) = ov;
    }
    // phase C: S^T := gC * S^T + v_new^T @ wkg
#pragma unroll
    for (int nt = 0; nt < 4; ++nt) {
#pragma unroll
      for (int r = 0; r < 4; ++r) Sacc[nt][r] *= gC;
#pragma unroll
      for (int kt = 0; kt < 2; ++kt) Sacc[nt] = mfma16(aV[kt], c_wkg[nt * 2 + kt], Sacc[nt]);
#pragma unroll
      for (int r = 0; r < 4; ++r)
        STb[quad * 4 + r][w * 64 + nt * 16 + lane15] = f2bf(Sacc[nt][r]);
    }
  }
}

extern "C" void kernel_launch(void* const* d_in, const int* in_sizes, int n_in,
                              void* d_out, int out_size, void* d_ws, size_t ws_size,
                              hipStream_t stream) {
  const float* x = (const float*)d_in[0];
  const float* Ww = (const float*)d_in[1];
  const float* Wr = (const float*)d_in[2];
  const float* decay = (const float*)d_in[3];
  const float* lalpha = (const float*)d_in[4];

  char* ws = (char*)d_ws;
  size_t off = 0;
  auto alloc = [&](size_t bytes) {
    char* p = ws + off;
    off += (bytes + 255) & ~(size_t)255;
    return p;
  };
  u16* xb16 = (u16*)alloc(33554432);   // (B,T,D) bf16 x   (later aliased as o)
  u16* rk16 = (u16*)alloc(33554432);   // (B,T,D) bf16 rk
  u16* v16  = (u16*)alloc(33554432);   // (B,T,D) bf16 v
  u16* vAb  = (u16*)alloc(33554432);   // (BH,N,C,d)
  u16* wkAb = (u16*)alloc(33554432);   // (BH,N,C,d)
  u16* wkgb = (u16*)alloc(33554432);   // (BH,N,d,C)
  u16* intrb = (u16*)alloc(8388608);   // (BH,N,C,C)
  u16* Ww16 = (u16*)alloc(2097152);
  u16* Wr16 = (u16*)alloc(2097152);
  u16* o16 = xb16;  // alias: xb16 dead after GEMM1

  kconv<<<1024, 256, 0, stream>>>(Ww, Ww16, 262144);
  kconv<<<1024, 256, 0, stream>>>(Wr, Wr16, 262144);
  k_rk<<<16384, 256, 0, stream>>>(x, xb16, rk16);
  gemm_bt<true><<<1024, 256, 0, stream>>>(xb16, Ww16, v16, nullptr, nullptr, 16384, 1024, 1024);
  k2<<<1024, 256, 0, stream>>>(rk16, v16, vAb, wkAb, wkgb, intrb, decay);
  k3<<<128, 256, 0, stream>>>(rk16, vAb, wkAb, wkgb, intrb, decay, lalpha, o16);
  gemm_bt<false><<<1024, 256, 0, stream>>>(o16, Wr16, nullptr, (float*)d_out, x, 16384, 1024, 1024);
}

// Round 3
// 839.809 us; speedup vs baseline: 1.5519x; 1.2418x over previous
//
#include <hip/hip_runtime.h>
#include <stdint.h>

typedef unsigned short u16;
typedef unsigned int u32;
typedef __attribute__((ext_vector_type(8))) short bf16x8;
typedef __attribute__((ext_vector_type(4))) float f32x4;

#define T_SEQ 8192
#define DM 1024
#define HD 256

__device__ __forceinline__ u16 f2bf(float f) {
  u32 u = __float_as_uint(f);
  u32 r = (u + 0x7fffu + ((u >> 16) & 1u)) >> 16;
  return (u16)r;
}
__device__ __forceinline__ float bf2f(u16 u) {
  return __uint_as_float(((u32)u) << 16);
}
__device__ __forceinline__ f32x4 mfma16(bf16x8 a, bf16x8 b, f32x4 c) {
  return __builtin_amdgcn_mfma_f32_16x16x32_bf16(a, b, c, 0, 0, 0);
}
// async global->LDS, 16B per lane. LDS dest must be wave-uniform base + lane*16.
__device__ __forceinline__ void gl2lds16(const u16* g, u16* l) {
  __builtin_amdgcn_global_load_lds(
      (const __attribute__((address_space(1))) u32*)(uintptr_t)g,
      (__attribute__((address_space(3))) u32*)(u32)(uintptr_t)l, 16, 0, 0);
}

// ---------------- fp32 -> bf16 bulk convert ----------------
__global__ __launch_bounds__(256) void kconv(const float* __restrict__ src, u16* __restrict__ dst, int n4) {
  int i = blockIdx.x * 256 + threadIdx.x;
  if (i < n4) {
    float4 v = reinterpret_cast<const float4*>(src)[i];
    ushort4 s;
    s.x = f2bf(v.x); s.y = f2bf(v.y); s.z = f2bf(v.z); s.w = f2bf(v.w);
    reinterpret_cast<ushort4*>(dst)[i] = s;
  }
}

// ---------------- K1: xb16 + per-head-normalized rk (both (B,T,D) bf16) ----------------
__global__ __launch_bounds__(256) void k_rk(const float* __restrict__ x, u16* __restrict__ xb, u16* __restrict__ rk) {
  const int row = blockIdx.x;
  const int t = threadIdx.x;
  const size_t base = (size_t)row * DM + t * 4;
  float4 v = *reinterpret_cast<const float4*>(&x[base]);
  ushort4 s;
  s.x = f2bf(v.x); s.y = f2bf(v.y); s.z = f2bf(v.z); s.w = f2bf(v.w);
  *reinterpret_cast<ushort4*>(&xb[base]) = s;
  float ss = v.x * v.x + v.y * v.y + v.z * v.z + v.w * v.w;
#pragma unroll
  for (int m = 1; m < 64; m <<= 1) ss += __shfl_xor(ss, m, 64);
  float inv = 1.0f / fmaxf(sqrtf(ss), 1e-12f);
  ushort4 r;
  r.x = f2bf(v.x * inv); r.y = f2bf(v.y * inv); r.z = f2bf(v.z * inv); r.w = f2bf(v.w * inv);
  *reinterpret_cast<ushort4*>(&rk[base]) = r;
}

// ---------------- GEMM: C[M,N] = A[M,K] @ Bt[N,K]^T (bf16 in, fp32 acc) ----------------
template <bool STORE_BF16>
__global__ __launch_bounds__(256) void gemm_bt(const u16* __restrict__ A, const u16* __restrict__ Bt,
                                               u16* __restrict__ Cb, float* __restrict__ Cf,
                                               const float* __restrict__ addin, int M, int N, int K) {
  __shared__ __align__(16) u16 As[128 * 64];
  __shared__ __align__(16) u16 Bs[128 * 64];
  const int tiles_n = N >> 7;
  const int tm = (blockIdx.x / tiles_n) << 7;
  const int tn = (blockIdx.x % tiles_n) << 7;
  const int t = threadIdx.x;
  const int w = t >> 6, l = t & 63;
  const int lane15 = l & 15, quad = l >> 4;
  const int wm = w & 1, wn = w >> 1;
  const int r0 = t >> 3;          // 0..31
  const int kc = (t & 7) << 3;    // 0..56 (u16 units, 16B chunks)

  f32x4 acc[4][4];
#pragma unroll
  for (int mi = 0; mi < 4; ++mi)
#pragma unroll
    for (int ni = 0; ni < 4; ++ni) acc[mi][ni] = (f32x4){0.f, 0.f, 0.f, 0.f};

  const int NK = K >> 6;
#pragma unroll 1
  for (int kt = 0; kt < NK; ++kt) {
    __syncthreads();
    const int k0 = kt << 6;
#pragma unroll
    for (int j = 0; j < 4; ++j) {
      gl2lds16(&A[(size_t)(tm + r0 + j * 32) * K + k0 + kc], &As[(r0 + j * 32) * 64 + kc]);
      gl2lds16(&Bt[(size_t)(tn + r0 + j * 32) * K + k0 + kc], &Bs[(r0 + j * 32) * 64 + kc]);
    }
    __syncthreads();
#pragma unroll
    for (int kk = 0; kk < 2; ++kk) {
      bf16x8 af[4], bfr[4];
#pragma unroll
      for (int mi = 0; mi < 4; ++mi)
        af[mi] = *reinterpret_cast<const bf16x8*>(&As[(wm * 64 + mi * 16 + lane15) * 64 + kk * 32 + quad * 8]);
#pragma unroll
      for (int ni = 0; ni < 4; ++ni)
        bfr[ni] = *reinterpret_cast<const bf16x8*>(&Bs[(wn * 64 + ni * 16 + lane15) * 64 + kk * 32 + quad * 8]);
#pragma unroll
      for (int mi = 0; mi < 4; ++mi)
#pragma unroll
        for (int ni = 0; ni < 4; ++ni) acc[mi][ni] = mfma16(af[mi], bfr[ni], acc[mi][ni]);
    }
  }
#pragma unroll
  for (int mi = 0; mi < 4; ++mi)
#pragma unroll
    for (int ni = 0; ni < 4; ++ni)
#pragma unroll
      for (int r = 0; r < 4; ++r) {
        int row = tm + wm * 64 + mi * 16 + quad * 4 + r;
        int col = tn + wn * 64 + ni * 16 + lane15;
        size_t idx = (size_t)row * N + col;
        float vv = acc[mi][ni][r];
        if (STORE_BF16) Cb[idx] = f2bf(vv);
        else Cf[idx] = vv + addin[idx];
      }
}

// ---------------- K2 (MFMA rewrite): per-chunk A0, blocked inv, intra, vA, wkA, wkgT ----------------
// One block per (bh, n) chunk. 256 threads = 4 waves. ~111 KB LDS -> 1 block/CU.
__global__ __launch_bounds__(256, 1) void k2(const u16* __restrict__ rk, const u16* __restrict__ v,
                                             u16* __restrict__ vA, u16* __restrict__ wkA,
                                             u16* __restrict__ wkgT, u16* __restrict__ intra,
                                             const float* __restrict__ decay) {
  __shared__ __align__(16) u16 sk[65][264];     // wk_ext rows (row r = token n*64-1+r), bf16
  __shared__ __align__(16) u16 tT[256][72];     // transposed operand (wkT, then vT)
  __shared__ __align__(16) float Am[64][68];    // A0 (strict lower valid), f32
  __shared__ __align__(16) float Xm[64][68];    // X = inv(I - A0), full explicit
  __shared__ __align__(16) float tmpT[4][16][20];
  __shared__ float gp[65];
  const int bx = blockIdx.x;
  const int bh = bx >> 7, n = bx & 127;
  const int b = bh >> 2, h = bh & 3;
  const int t = threadIdx.x;
  const int w = t >> 6, l = t & 63;
  const int lane15 = l & 15, quad = l >> 4;
  const int li = l & 15, jq = l >> 4;

  if (t <= 64) {
    float gamma = 1.0f / (1.0f + __expf(-decay[h]));
    gp[t] = __powf(gamma, (float)t);
  }
  // zero Am, Xm (incl pad)
  for (int i = t; i < 64 * 68; i += 256) {
    (&Am[0][0])[i] = 0.0f;
    (&Xm[0][0])[i] = 0.0f;
  }
  // stage sk (row-major) + wkT (transposed) from global rk
  for (int i = t; i < 65 * 32; i += 256) {
    const int r = i >> 5, c16 = i & 31;
    const int g = n * 64 - 1 + r;
    uint4 val = make_uint4(0, 0, 0, 0);
    if (g >= 0) val = *reinterpret_cast<const uint4*>(&rk[((size_t)(b * T_SEQ + g)) * DM + h * HD + c16 * 8]);
    *reinterpret_cast<uint4*>(&sk[r][c16 * 8]) = val;
    if (r < 64) {
      u16 e[8];
      e[0] = val.x & 0xffff; e[1] = val.x >> 16;
      e[2] = val.y & 0xffff; e[3] = val.y >> 16;
      e[4] = val.z & 0xffff; e[5] = val.z >> 16;
      e[6] = val.w & 0xffff; e[7] = val.w >> 16;
#pragma unroll
      for (int ee = 0; ee < 8; ++ee) tT[c16 * 8 + ee][r] = e[ee];
    }
  }
  __syncthreads();

  // ---- step 1: M_ww = wk@wk^T (waves 0,1), M_rw = rk@wk^T (waves 2,3) via MFMA ----
  {
    const int prod = w >> 1;          // 0: ww, 1: rw
    const int tib = (w & 1) * 2;      // ti in {tib, tib+1}
    f32x4 s1[2][4];
#pragma unroll
    for (int a = 0; a < 2; ++a)
#pragma unroll
      for (int tj = 0; tj < 4; ++tj) s1[a][tj] = (f32x4){0.f, 0.f, 0.f, 0.f};
#pragma unroll
    for (int ks = 0; ks < 8; ++ks) {
      bf16x8 afr[2], bfr[4];
#pragma unroll
      for (int a = 0; a < 2; ++a)
        afr[a] = *reinterpret_cast<const bf16x8*>(&sk[(tib + a) * 16 + lane15 + prod][ks * 32 + quad * 8]);
#pragma unroll
      for (int tj = 0; tj < 4; ++tj)
        bfr[tj] = *reinterpret_cast<const bf16x8*>(&sk[tj * 16 + lane15][ks * 32 + quad * 8]);
#pragma unroll
      for (int a = 0; a < 2; ++a)
#pragma unroll
        for (int tj = 0; tj < 4; ++tj) s1[a][tj] = mfma16(afr[a], bfr[tj], s1[a][tj]);
    }
    if (prod == 0) {
#pragma unroll
      for (int a = 0; a < 2; ++a)
#pragma unroll
        for (int tj = 0; tj < 4; ++tj)
#pragma unroll
          for (int r = 0; r < 4; ++r) {
            const int i = (tib + a) * 16 + quad * 4 + r, j = tj * 16 + lane15;
            if (j < i) Am[i][j] = -s1[a][tj][r] * gp[i - j];
          }
    } else {
      u16* intra_n = intra + (size_t)bx * 4096;
#pragma unroll
      for (int a = 0; a < 2; ++a)
#pragma unroll
        for (int tj = 0; tj < 4; ++tj)
#pragma unroll
          for (int r = 0; r < 4; ++r) {
            const int i = (tib + a) * 16 + quad * 4 + r, j = tj * 16 + lane15;
            intra_n[i * 64 + j] = (j < i) ? f2bf(s1[a][tj][r] * gp[i - j]) : (u16)0;
          }
    }
  }
  __syncthreads();

  // ---- step 2a: invert diagonal 16x16 blocks (wave w -> block w), column-parallel ----
  if (l < 16) {
    const int bi = w * 16;
    const int j = l;
    Xm[bi + j][bi + j] = 1.0f;
    for (int i = 1; i < 16; ++i) {
      if (j < i) {
        float acc = Am[bi + i][bi + j];
        for (int k = j + 1; k < i; ++k) acc += Am[bi + i][bi + k] * Xm[bi + k][bi + j];
        Xm[bi + i][bi + j] = acc;
      }
    }
  }
  __syncthreads();

  // ---- step 2b: off-diagonal blocks, levels 1..3: X(I,J) = X(I,I) * sum_K A0(I,K) X(K,J) ----
  for (int lvl = 1; lvl < 4; ++lvl) {
    if (w + lvl < 4) {
      const int I = w + lvl, J = w;
      float a4[4] = {0.f, 0.f, 0.f, 0.f};
      for (int K = J; K < I; ++K) {
#pragma unroll
        for (int k = 0; k < 16; ++k) {
          const float a = Am[I * 16 + li][K * 16 + k];
          const float* xr = &Xm[K * 16 + k][J * 16 + jq * 4];
          a4[0] += a * xr[0]; a4[1] += a * xr[1]; a4[2] += a * xr[2]; a4[3] += a * xr[3];
        }
      }
#pragma unroll
      for (int r = 0; r < 4; ++r) tmpT[w][li][jq * 4 + r] = a4[r];
      asm volatile("" ::: "memory");
      float b4[4] = {0.f, 0.f, 0.f, 0.f};
#pragma unroll
      for (int k = 0; k < 16; ++k) {
        const float a = Xm[I * 16 + li][I * 16 + k];
        const float* tr = &tmpT[w][k][jq * 4];
        b4[0] += a * tr[0]; b4[1] += a * tr[1]; b4[2] += a * tr[2]; b4[3] += a * tr[3];
      }
#pragma unroll
      for (int r = 0; r < 4; ++r) Xm[I * 16 + li][J * 16 + jq * 4 + r] = b4[r];
    }
    __syncthreads();
  }

  // ---- step 3: products X @ wk (then X @ v) via MFMA; output (C x d) row-major bf16 ----
  auto product = [&](u16* dst) {
    bf16x8 afr[2];
#pragma unroll
    for (int ks = 0; ks < 2; ++ks) {
      const float* xr = &Xm[w * 16 + lane15][ks * 32 + quad * 8];
      bf16x8 f;
#pragma unroll
      for (int e = 0; e < 8; ++e) ((u16*)&f)[e] = f2bf(xr[e]);
      afr[ks] = f;
    }
#pragma unroll
    for (int nj = 0; nj < 16; ++nj) {
      f32x4 acc = (f32x4){0.f, 0.f, 0.f, 0.f};
#pragma unroll
      for (int ks = 0; ks < 2; ++ks) {
        bf16x8 bfr = *reinterpret_cast<const bf16x8*>(&tT[nj * 16 + lane15][ks * 32 + quad * 8]);
        acc = mfma16(afr[ks], bfr, acc);
      }
#pragma unroll
      for (int r = 0; r < 4; ++r)
        dst[(size_t)(w * 16 + quad * 4 + r) * 256 + nj * 16 + lane15] = f2bf(acc[r]);
    }
  };
  product(wkA + (size_t)bx * (64 * 256));
  // wkgT[i][c] = wk[c][i] * gamma^(63-c) = wkT[i][c] * gp[63-c], layout (d, C)
  {
    u16* wkg_n = wkgT + (size_t)bx * (256 * 64);
    const int i = t;
#pragma unroll
    for (int c16 = 0; c16 < 8; ++c16) {
      bf16x8 rv = *reinterpret_cast<const bf16x8*>(&tT[i][c16 * 8]);
      bf16x8 ov;
#pragma unroll
      for (int e = 0; e < 8; ++e)
        ((u16*)&ov)[e] = f2bf(bf2f(((u16*)&rv)[e]) * gp[63 - (c16 * 8 + e)]);
      *reinterpret_cast<bf16x8*>(&wkg_n[i * 64 + c16 * 8]) = ov;
    }
  }
  __syncthreads();  // all tT (wkT) reads done
  // stage vT
  for (int i = t; i < 64 * 32; i += 256) {
    const int r = i >> 5, c16 = i & 31;
    uint4 val = *reinterpret_cast<const uint4*>(&v[((size_t)(b * T_SEQ + n * 64 + r)) * DM + h * HD + c16 * 8]);
    u16 e[8];
    e[0] = val.x & 0xffff; e[1] = val.x >> 16;
    e[2] = val.y & 0xffff; e[3] = val.y >> 16;
    e[4] = val.z & 0xffff; e[5] = val.z >> 16;
    e[6] = val.w & 0xffff; e[7] = val.w >> 16;
#pragma unroll
    for (int ee = 0; ee < 8; ++ee) tT[c16 * 8 + ee][r] = e[ee];
  }
  __syncthreads();
  product(vA + (size_t)bx * (64 * 256));
}

// ---------------- K3: sequential scan; XCD-swizzled; all step loads issued at loop top ----------------
__global__ __launch_bounds__(256, 1) void k3(const u16* __restrict__ rk, const u16* __restrict__ vA,
                                             const u16* __restrict__ wkA, const u16* __restrict__ wkgT,
                                             const u16* __restrict__ intra, const float* __restrict__ decay,
                                             const float* __restrict__ log_alpha, u16* __restrict__ o) {
  __shared__ __align__(16) u16 STb[16][264];   // S^T bf16 copy: [jl][i], padded
  __shared__ __align__(16) u16 vnT[16][72];    // v_new^T [jl][c]
  // XCD swizzle: all 16 column-block WGs of one bh land on the same XCD (round-robin dispatch)
  const int bh = blockIdx.x & 7, jb = blockIdx.x >> 3;
  const int b = bh >> 2, h = bh & 3;
  const int j0 = jb << 4;
  const int t = threadIdx.x, w = t >> 6, l = t & 63;
  const int lane15 = l & 15, quad = l >> 4;
  const float gamma = 1.0f / (1.0f + __expf(-decay[h]));
  const float alpha = __expf(log_alpha[h]);
  const float gC = __powf(gamma, 64.0f);
  const int c = w * 16 + lane15;               // chunk-row this lane owns in phases A/B
  const float gc = __powf(gamma, (float)c);
  for (int i = t; i < 2112; i += 256) reinterpret_cast<u32*>(&STb[0][0])[i] = 0u;
  f32x4 Sacc[4];
#pragma unroll
  for (int nt = 0; nt < 4; ++nt) Sacc[nt] = (f32x4){0.f, 0.f, 0.f, 0.f};

  const size_t chb = (size_t)bh * 128;
  const u16* wkA_b = wkA + chb * (64 * 256);
  const u16* vA_b = vA + chb * (64 * 256);
  const u16* wkg_b = wkgT + chb * (256 * 64);
  const u16* intr_b = intra + chb * 4096;
  const u16* rk_b = rk + ((size_t)(b * T_SEQ)) * DM + h * HD;

#pragma unroll 1
  for (int n = 0; n < 128; ++n) {
    __syncthreads();  // (a) STb from prev step's phase C stable
    // ---- issue ALL of this step's global loads up front (within-iteration lifetime) ----
    const u16* wkA_n = wkA_b + (size_t)n * (64 * 256);
    const u16* vA_n = vA_b + (size_t)n * (64 * 256);
    const u16* wkg_n = wkg_b + (size_t)n * (256 * 64);
    const u16* intr_n = intr_b + (size_t)n * 4096;
    const u16* rk_n = rk_b + (size_t)n * 64 * DM;
    bf16x8 c_wkA[8], c_rk[8], c_wkg[8], c_in[2];
    ushort4 c_vA;
    {
      const u16* wrow = wkA_n + c * 256 + quad * 8;
#pragma unroll
      for (int kt = 0; kt < 8; ++kt) c_wkA[kt] = *reinterpret_cast<const bf16x8*>(&wrow[kt * 32]);
      c_vA = *reinterpret_cast<const ushort4*>(&vA_n[c * 256 + j0 + quad * 4]);
      const u16* rrow = rk_n + (size_t)c * DM + quad * 8;
#pragma unroll
      for (int kt = 0; kt < 8; ++kt) c_rk[kt] = *reinterpret_cast<const bf16x8*>(&rrow[kt * 32]);
      const u16* irow = intr_n + c * 64 + quad * 8;
#pragma unroll
      for (int kt = 0; kt < 2; ++kt) c_in[kt] = *reinterpret_cast<const bf16x8*>(&irow[kt * 32]);
#pragma unroll
      for (int nt = 0; nt < 4; ++nt)
#pragma unroll
        for (int kt = 0; kt < 2; ++kt)
          c_wkg[nt * 2 + kt] =
              *reinterpret_cast<const bf16x8*>(&wkg_n[(size_t)(w * 64 + nt * 16 + lane15) * 64 + kt * 32 + quad * 8]);
    }
    bf16x8 aS[8];
#pragma unroll
    for (int kt = 0; kt < 8; ++kt)
      aS[kt] = *reinterpret_cast<const bf16x8*>(&STb[lane15][kt * 32 + quad * 8]);
    // phase A: P^T = S^T @ wkA^T; v_new^T = vA^T - P^T
    f32x4 accA = (f32x4){0.f, 0.f, 0.f, 0.f};
#pragma unroll
    for (int kt = 0; kt < 8; ++kt) accA = mfma16(aS[kt], c_wkA[kt], accA);
    vnT[quad * 4 + 0][c] = f2bf(bf2f(c_vA.x) - accA[0]);
    vnT[quad * 4 + 1][c] = f2bf(bf2f(c_vA.y) - accA[1]);
    vnT[quad * 4 + 2][c] = f2bf(bf2f(c_vA.z) - accA[2]);
    vnT[quad * 4 + 3][c] = f2bf(bf2f(c_vA.w) - accA[3]);
    __syncthreads();  // (b) vnT visible
    bf16x8 aV[2];
#pragma unroll
    for (int kt = 0; kt < 2; ++kt)
      aV[kt] = *reinterpret_cast<const bf16x8*>(&vnT[lane15][kt * 32 + quad * 8]);
    // phase B: o^T = diag(g^c)*(S^T @ rk^T) + v_new^T @ intra^T, *alpha, direct store
    {
      f32x4 accO = (f32x4){0.f, 0.f, 0.f, 0.f};
#pragma unroll
      for (int kt = 0; kt < 8; ++kt) accO = mfma16(aS[kt], c_rk[kt], accO);
#pragma unroll
      for (int r = 0; r < 4; ++r) accO[r] *= gc;
#pragma unroll
      for (int kt = 0; kt < 2; ++kt) accO = mfma16(aV[kt], c_in[kt], accO);
      ushort4 ov;
      ov.x = f2bf(accO[0] * alpha);
      ov.y = f2bf(accO[1] * alpha);
      ov.z = f2bf(accO[2] * alpha);
      ov.w = f2bf(accO[3] * alpha);
      *reinterpret_cast<ushort4*>(&o[((size_t)(b * T_SEQ + n * 64 + c)) * DM + h * HD + j0 + quad * 4]) = ov;
    }
    // phase C: S^T := gC * S^T + v_new^T @ wkg
#pragma unroll
    for (int nt = 0; nt < 4; ++nt) {
#pragma unroll
      for (int r = 0; r < 4; ++r) Sacc[nt][r] *= gC;
#pragma unroll
      for (int kt = 0; kt < 2; ++kt) Sacc[nt] = mfma16(aV[kt], c_wkg[nt * 2 + kt], Sacc[nt]);
#pragma unroll
      for (int r = 0; r < 4; ++r)
        STb[quad * 4 + r][w * 64 + nt * 16 + lane15] = f2bf(Sacc[nt][r]);
    }
  }
}

extern "C" void kernel_launch(void* const* d_in, const int* in_sizes, int n_in,
                              void* d_out, int out_size, void* d_ws, size_t ws_size,
                              hipStream_t stream) {
  const float* x = (const float*)d_in[0];
  const float* Ww = (const float*)d_in[1];
  const float* Wr = (const float*)d_in[2];
  const float* decay = (const float*)d_in[3];
  const float* lalpha = (const float*)d_in[4];

  char* ws = (char*)d_ws;
  size_t off = 0;
  auto alloc = [&](size_t bytes) {
    char* p = ws + off;
    off += (bytes + 255) & ~(size_t)255;
    return p;
  };
  u16* xb16 = (u16*)alloc(33554432);   // (B,T,D) bf16 x   (later aliased as o)
  u16* rk16 = (u16*)alloc(33554432);   // (B,T,D) bf16 rk
  u16* v16  = (u16*)alloc(33554432);   // (B,T,D) bf16 v
  u16* vAb  = (u16*)alloc(33554432);   // (BH,N,C,d)
  u16* wkAb = (u16*)alloc(33554432);   // (BH,N,C,d)
  u16* wkgb = (u16*)alloc(33554432);   // (BH,N,d,C)
  u16* intrb = (u16*)alloc(8388608);   // (BH,N,C,C)
  u16* Ww16 = (u16*)alloc(2097152);
  u16* Wr16 = (u16*)alloc(2097152);
  u16* o16 = xb16;  // alias: xb16 dead after GEMM1

  kconv<<<1024, 256, 0, stream>>>(Ww, Ww16, 262144);
  kconv<<<1024, 256, 0, stream>>>(Wr, Wr16, 262144);
  k_rk<<<16384, 256, 0, stream>>>(x, xb16, rk16);
  gemm_bt<true><<<1024, 256, 0, stream>>>(xb16, Ww16, v16, nullptr, nullptr, 16384, 1024, 1024);
  k2<<<1024, 256, 0, stream>>>(rk16, v16, vAb, wkAb, wkgb, intrb, decay);
  k3<<<128, 256, 0, stream>>>(rk16, vAb, wkAb, wkgb, intrb, decay, lalpha, o16);
  gemm_bt<false><<<1024, 256, 0, stream>>>(o16, Wr16, nullptr, (float*)d_out, x, 16384, 1024, 1024);
}